// Round 13
// baseline (721.503 us; speedup 1.0000x reference)
//
#include <hip/hip_runtime.h>
#include <math.h>

// Problem constants (B=2, T=2048, DIM=2048, HEADS=16, HEAD_DIM=128, N_KV=4,
// LATENT=512, SEL_TOPK=64, SEL_DIM=64, SOFTCAP=30, EPS=1e-6)
#define T_SEQ 2048
#define BATCH 2
#define NHEADS 16
#define HD 128
#define NKV 4

typedef __bf16 bf16x8 __attribute__((ext_vector_type(8)));
typedef float f32x4 __attribute__((ext_vector_type(4)));

__device__ inline unsigned short bf16rne(float f) {
  unsigned u = __float_as_uint(f);
  unsigned r = (u + 0x7FFFu + ((u >> 16) & 1u)) >> 16;
  return (unsigned short)r;
}

__device__ inline float bflo(unsigned u) {          // low bf16 of a dword
  return __uint_as_float(u << 16);
}
__device__ inline float bfhi(unsigned u) {          // high bf16 of a dword
  return __uint_as_float(u & 0xFFFF0000u);
}

__device__ inline void gload_lds16(const void* g, void* l) {
  __builtin_amdgcn_global_load_lds(
      (__attribute__((address_space(1))) void*)const_cast<void*>(g),
      (__attribute__((address_space(3))) void*)l, 16, 0, 0);
}

// monotonic encoding: enc(a) < enc(b) <=> a < b (floats, -inf ok)
#define ENC_NEGINF 0x007FFFFFu
__device__ inline unsigned enc32(float v) {
  unsigned u = __float_as_uint(v);
  return (u & 0x80000000u) ? ~u : (u | 0x80000000u);
}

// ---------------------------------------------------------------------------
// RoPE table: tab[t][i] = (cos, sin), i = pair index 0..63. numpy fp32 op
// order: y=fl32(10000^x) (double pow), inv=1/y (fp32), angle=fl32(t*inv).
// ---------------------------------------------------------------------------
__global__ void rope_table_kernel(float* __restrict__ tab) {
  int t = blockIdx.x;
  int i = threadIdx.x;                 // 0..63
  int j = (2 * i) & 63;
  float y = (float)pow(10000.0, (double)j / 64.0);
  float invf = 1.0f / y;
  float angle = (float)t * invf;
  double a = (double)angle;
  tab[(t * 64 + i) * 2 + 0] = (float)cos(a);
  tab[(t * 64 + i) * 2 + 1] = (float)sin(a);
}

// ---------------------------------------------------------------------------
// RMSNorm (128 dims) + interleaved RoPE, in place. EXACT variant (LDS-tree
// reduction order frozen — feeds the selection-exact path). qsel only.
// ---------------------------------------------------------------------------
__global__ __launch_bounds__(128) void norm_rope_kernel(
    float* __restrict__ base, const float* __restrict__ w,
    const float* __restrict__ tab, int Hloc, int rowStride) {
  int blk = blockIdx.x;
  int h = blk % Hloc;
  int bt = blk / Hloc;
  int t = bt & (T_SEQ - 1);
  float* row = base + (size_t)bt * rowStride + h * HD;
  int d = threadIdx.x;
  float v = row[d];
  __shared__ float red[128];
  red[d] = v * v;
  __syncthreads();
#pragma unroll
  for (int off = 64; off > 0; off >>= 1) {
    if (d < off) red[d] += red[d + off];
    __syncthreads();
  }
  float ssum = red[0];
  __syncthreads();
  float inv = 1.0f / sqrtf(ssum / 128.0f + 1e-6f);
  float xn = v * inv * w[d];
  red[d] = xn;
  __syncthreads();
  int p = d >> 1;
  float c  = tab[(t * 64 + p) * 2 + 0];
  float sn = tab[(t * 64 + p) * 2 + 1];
  float x1 = red[p * 2], x2 = red[p * 2 + 1];
  row[d] = ((d & 1) == 0) ? (x1 * c - x2 * sn) : (x1 * sn + x2 * c);
}

// ---------------------------------------------------------------------------
// kv RMSNorm+RoPE: EXACT fp32 path identical to norm_rope_kernel (Hloc=4,
// rowStride=1024), plus pure epilogue: bf16 of the normed k slice AND bf16
// convert of the matching raw V slice into kvb. Kills the separate convert.
// ---------------------------------------------------------------------------
__global__ __launch_bounds__(128) void kvnorm_rope_kernel(
    float* __restrict__ base, const float* __restrict__ w,
    const float* __restrict__ tab, unsigned short* __restrict__ kvb) {
  int blk = blockIdx.x;              // bt*4 + h
  int h = blk % 4;
  int bt = blk / 4;
  int t = bt & (T_SEQ - 1);
  float* row = base + (size_t)bt * 1024 + h * HD;
  int d = threadIdx.x;
  float v = row[d];
  __shared__ float red[128];
  red[d] = v * v;
  __syncthreads();
#pragma unroll
  for (int off = 64; off > 0; off >>= 1) {
    if (d < off) red[d] += red[d + off];
    __syncthreads();
  }
  float ssum = red[0];
  __syncthreads();
  float inv = 1.0f / sqrtf(ssum / 128.0f + 1e-6f);
  float xn = v * inv * w[d];
  red[d] = xn;
  __syncthreads();
  int p = d >> 1;
  float c  = tab[(t * 64 + p) * 2 + 0];
  float sn = tab[(t * 64 + p) * 2 + 1];
  float x1 = red[p * 2], x2 = red[p * 2 + 1];
  float out = ((d & 1) == 0) ? (x1 * c - x2 * sn) : (x1 * sn + x2 * c);
  row[d] = out;
  size_t kb = (size_t)bt * 1024 + h * HD + d;
  kvb[kb] = bf16rne(out);
  float vv = base[(size_t)bt * 1024 + 512 + h * HD + d];   // raw V slice
  kvb[(size_t)bt * 1024 + 512 + h * HD + d] = bf16rne(vv);
}

// ---------------------------------------------------------------------------
// q RMSNorm+RoPE: wave-per-row, shuffle reduce, no LDS/barriers. q feeds
// only the tanh/softmax attention path (bf16-tolerant) — reduction-order
// change is safe here (NOT used for selection).
// ---------------------------------------------------------------------------
__global__ __launch_bounds__(256) void qnorm_rope_kernel(
    float* __restrict__ base, const float* __restrict__ w,
    const float* __restrict__ tab) {
  int row = blockIdx.x * 4 + (threadIdx.x >> 6);   // over BT*16 rows
  int lane = threadIdx.x & 63;
  int h = row & 15;
  int bt = row >> 4;
  int t = bt & (T_SEQ - 1);
  float* rp = base + (size_t)bt * 2048 + h * HD;
  float2 v = *(const float2*)(rp + 2 * lane);
  float ss = v.x * v.x + v.y * v.y;
#pragma unroll
  for (int off = 32; off > 0; off >>= 1) ss += __shfl_xor(ss, off);
  float inv = 1.0f / sqrtf(ss / 128.0f + 1e-6f);
  float2 wv = *(const float2*)(w + 2 * lane);
  float x1 = v.x * inv * wv.x;
  float x2 = v.y * inv * wv.y;
  float2 cs = *(const float2*)(tab + (t * 64 + lane) * 2);
  float2 o;
  o.x = x1 * cs.x - x2 * cs.y;
  o.y = x1 * cs.y + x2 * cs.x;
  *(float2*)(rp + 2 * lane) = o;
}

// ---------------------------------------------------------------------------
// fp32 GEMM body (PROVEN sgemm3: 187.5us/47%VALU — structural LDS-pipe cap).
// 64x64 tile, BK=16, 256 threads, 4x4 microtile, register prefetch.
// Per-output summation order IDENTICAL: k sequential 0..K-1,
// acc[i][j] += a[i]*b[j] (selection-exactness frozen). Block mapping is
// resolved by the CALLER.
// ---------------------------------------------------------------------------
#define BKG 16
__device__ __forceinline__ void sgemm_body(
    const float* __restrict__ A, const float* __restrict__ W,
    const float* __restrict__ bias, float* __restrict__ C,
    int ldw, int ldc, int n0, int m0, int K, char* smem) {
  float (*As)[68] = (float (*)[68])smem;               // 16*68*4 = 4352 B
  float (*Bs)[68] = (float (*)[68])(smem + 4352);      // 4352 B
  int tid = threadIdx.x;
  int tx = tid & 15;
  int ty = tid >> 4;
  int ar = tid >> 2, ac = (tid & 3) * 4;
  int brr = tid >> 4, bc = (tid & 15) * 4;
  const float* Ap = A + (size_t)(m0 + ar) * K + ac;
  const float* Wp = W + (size_t)brr * ldw + n0 + bc;
  float acc[4][4] = {};
  // prologue: stage tile k0=0 into registers
  float4 av = *(const float4*)(Ap);
  float4 wv = *(const float4*)(Wp);
  for (int k0 = 0; k0 < K; k0 += BKG) {
    As[ac + 0][ar] = av.x; As[ac + 1][ar] = av.y;
    As[ac + 2][ar] = av.z; As[ac + 3][ar] = av.w;
    *(float4*)&Bs[brr][bc] = wv;
    __syncthreads();
    if (k0 + BKG < K) {               // prefetch next tile under compute
      av = *(const float4*)(Ap + k0 + BKG);
      wv = *(const float4*)(Wp + (size_t)(k0 + BKG) * ldw);
    }
#pragma unroll
    for (int kk = 0; kk < BKG; kk++) {
      float4 a = *(const float4*)&As[kk][ty * 4];
      float4 b = *(const float4*)&Bs[kk][tx * 4];
      float aa[4] = {a.x, a.y, a.z, a.w};
      float bb[4] = {b.x, b.y, b.z, b.w};
#pragma unroll
      for (int i = 0; i < 4; i++)
#pragma unroll
        for (int j = 0; j < 4; j++) acc[i][j] += aa[i] * bb[j];
    }
    __syncthreads();
  }
  float4 bv = *(const float4*)&bias[n0 + tx * 4];
  float bb[4] = {bv.x, bv.y, bv.z, bv.w};
#pragma unroll
  for (int i = 0; i < 4; i++) {
    float4 o;
    o.x = acc[i][0] + bb[0];
    o.y = acc[i][1] + bb[1];
    o.z = acc[i][2] + bb[2];
    o.w = acc[i][3] + bb[3];
    *(float4*)&C[(size_t)(m0 + ty * 4 + i) * ldc + n0 + tx * 4] = o;
  }
}

// ---------------------------------------------------------------------------
// Standalone fp32 GEMM (dual-source, 640-block grid) — REVERTED from fat1:
// merging with the MFMA GEMM raised VGPR 44->112 and throttled the sgemm
// waves (round 12: 242us > 222us sequential). Separate dispatch keeps
// VGPR=44 and the proven 187.5us operating point.
// ---------------------------------------------------------------------------
__global__ __launch_bounds__(256) void sgemm3_kernel(
    const float* __restrict__ A,
    const float* __restrict__ W1, const float* __restrict__ bias1,
    float* __restrict__ C1, int ldw1, int ldc1, int nx1,
    const float* __restrict__ W2, const float* __restrict__ bias2,
    float* __restrict__ C2, int ldw2, int ldc2, int K) {
  __shared__ __align__(16) char smem[8704];
  int bx = blockIdx.x;
  if (bx < nx1)
    sgemm_body(A, W1, bias1, C1, ldw1, ldc1, bx * 64, blockIdx.y * 64, K,
               smem);
  else
    sgemm_body(A, W2, bias2, C2, ldw2, ldc2, (bx - nx1) * 64,
               blockIdx.y * 64, K, smem);
}

// ---------------------------------------------------------------------------
// bf16 MFMA GEMM body: C[M,N] = A[M,K] @ BT[N,K]^T + bias, fp32 accumulate.
// 128x128 tile, BK=64, 4 waves, 16x16x32 MFMA, fragment-major LDS via
// global_load_lds(16B). Block mapping resolved by the caller.
// ---------------------------------------------------------------------------
__device__ __forceinline__ void mfma_body(
    const unsigned short* __restrict__ A,   // [M,K] bf16
    const unsigned short* __restrict__ BT,  // [N,K] bf16
    const float* __restrict__ bias,         // [N]
    float* __restrict__ C,                  // [M,N] fp32
    int N, int K, int m0, int n0, char* smem) {
  bf16x8 (*lA)[64] = (bf16x8 (*)[64])smem;             // 16 KB
  bf16x8 (*lB)[64] = (bf16x8 (*)[64])(smem + 16384);   // 16 KB
  int tid = threadIdx.x;
  int w = tid >> 6, lane = tid & 63;
  int wm = w >> 1, wn = w & 1;
  f32x4 acc[4][4] = {};
  int sr = lane & 15;
  int sk = (lane >> 4) * 8;
  const unsigned short* Abase = A + (size_t)(m0 + sr) * K + sk;
  const unsigned short* Bbase = BT + (size_t)(n0 + sr) * K + sk;

  for (int k0 = 0; k0 < K; k0 += 64) {
    __syncthreads();
#pragma unroll
    for (int c = 0; c < 4; c++) {
      int ch = w * 4 + c;
      int tt = ch >> 1, kk = ch & 1;
      gload_lds16(Abase + (size_t)(tt * 16) * K + k0 + kk * 32, &lA[ch][0]);
      gload_lds16(Bbase + (size_t)(tt * 16) * K + k0 + kk * 32, &lB[ch][0]);
    }
    __syncthreads();
#pragma unroll
    for (int kk = 0; kk < 2; kk++) {
      bf16x8 af[4], bfr[4];
#pragma unroll
      for (int t = 0; t < 4; t++) {
        af[t]  = lA[(wm * 4 + t) * 2 + kk][lane];
        bfr[t] = lB[(wn * 4 + t) * 2 + kk][lane];
      }
#pragma unroll
      for (int i = 0; i < 4; i++)
#pragma unroll
        for (int j = 0; j < 4; j++)
          acc[i][j] = __builtin_amdgcn_mfma_f32_16x16x32_bf16(
              af[i], bfr[j], acc[i][j], 0, 0, 0);
    }
  }
  int col0 = n0 + wn * 64 + (lane & 15);
  int row0 = m0 + wm * 64 + (lane >> 4) * 4;
#pragma unroll
  for (int j = 0; j < 4; j++) {
    float bv = bias[col0 + j * 16];
#pragma unroll
    for (int i = 0; i < 4; i++) {
#pragma unroll
      for (int r = 0; r < 4; r++)
        C[(size_t)(row0 + i * 16 + r) * N + col0 + j * 16] = acc[i][j][r] + bv;
    }
  }
}

// ---------------------------------------------------------------------------
// Standalone MFMA GEMM (q-proj, o-proj): XCD-aware swizzle (grid mult of 8).
// ---------------------------------------------------------------------------
__global__ __launch_bounds__(256) void mfma_gemm_bt(
    const unsigned short* __restrict__ A,
    const unsigned short* __restrict__ BT,
    const float* __restrict__ bias, float* __restrict__ C,
    int M, int N, int K) {
  __shared__ __align__(16) char smem[32768];
  int nb = gridDim.x * gridDim.y;
  int bid = blockIdx.y * gridDim.x + blockIdx.x;
  int cpx = nb >> 3;
  int sw = (bid & 7) * cpx + (bid >> 3);
  int bxs = sw % gridDim.x;
  int bys = sw / gridDim.x;
  mfma_body(A, BT, bias, C, N, K, bys * 128, bxs * 128, smem);
}

// ---------------------------------------------------------------------------
// FAT kernel 2 (KEPT from round 12 — contributed the net win): co-dispatch
// [kv-exact fp32 sgemm cols 0..127, 128 blocks] with [up-proj bf16 MFMA
// cols 128..1023, 224 blocks]. Column ranges DISJOINT (mfma col-block 0
// removed — redundant work). Same final kvbuf contents.
// ---------------------------------------------------------------------------
__global__ __launch_bounds__(256) void fat2_kernel(
    const float* __restrict__ dlat,
    const float* __restrict__ w_up, const float* __restrict__ b_up,
    float* __restrict__ kvbuf,
    const unsigned short* __restrict__ dlatb,
    const unsigned short* __restrict__ wupT) {
  __shared__ __align__(16) char smem[32768];
  int bid = blockIdx.x;
  if (bid < 128) {                    // exact fp32: cols 0..127, K=512
    int bx = bid & 1, by = bid >> 1;
    sgemm_body(dlat, w_up, b_up, kvbuf, 1024, 1024, bx * 64, by * 64, 512,
               smem);
  } else {                            // up-proj MFMA: col-blocks 1..7
    int mb = bid - 128;               // 0..223
    int bx = mb % 7, by = mb / 7;
    mfma_body(dlatb, wupT, b_up, kvbuf, 1024, 512, by * 128, (bx + 1) * 128,
              smem);
  }
}

// ---------------------------------------------------------------------------
// fp32 -> bf16 flat convert (RNE), 4 elems/thread.
// ---------------------------------------------------------------------------
__global__ __launch_bounds__(256) void convert_bf16_kernel(
    const float* __restrict__ X, unsigned short* __restrict__ Y, int n4) {
  int i = blockIdx.x * 256 + threadIdx.x;
  if (i >= n4) return;
  float4 v = ((const float4*)X)[i];
  ushort4 o;
  o.x = bf16rne(v.x); o.y = bf16rne(v.y);
  o.z = bf16rne(v.z); o.w = bf16rne(v.w);
  ((ushort4*)Y)[i] = o;
}

// ---------------------------------------------------------------------------
// fp32 [K,N] -> bf16 [N,K] transpose-convert, 32x32 LDS tile.
// ---------------------------------------------------------------------------
__global__ __launch_bounds__(256) void transpose_bf16_kernel(
    const float* __restrict__ W, unsigned short* __restrict__ WT,
    int K, int N) {
  __shared__ unsigned short t[32][33];
  int k0 = blockIdx.y * 32, n0 = blockIdx.x * 32;
  int tid = threadIdx.x;
#pragma unroll
  for (int i = 0; i < 4; i++) {
    int idx = tid + i * 256;
    int r = idx >> 5, c = idx & 31;
    t[c][r] = bf16rne(W[(size_t)(k0 + r) * N + n0 + c]);
  }
  __syncthreads();
#pragma unroll
  for (int i = 0; i < 4; i++) {
    int idx = tid + i * 256;
    int r = idx >> 5, c = idx & 31;
    WT[(size_t)(n0 + r) * K + k0 + c] = t[r][c];
  }
}

// ---------------------------------------------------------------------------
// Selection scores, BOTH batches in one dispatch (blockIdx.z = b).
// One 64x64 causal tile per block.
// S[b][r][c] = enc32( (q[r,0:64] . k[c,0:64]) * 0.125 ) for c<=r else NEGINF.
// ---------------------------------------------------------------------------
__global__ __launch_bounds__(256) void score_kernel(
    const float* __restrict__ qsel,   // [BT,128] (normed+roped head 0)
    const float* __restrict__ kv,     // [BT,1024] (post-norm; k head0 = 0:64)
    unsigned* __restrict__ S) {       // [2][2048][2048]
  int tc = blockIdx.x, tr = blockIdx.y;
  int b = blockIdx.z;
  if (tc > tr || tr == 0) return;     // causal; rows 0..63 use early path
  unsigned* Sb = S + (size_t)b * T_SEQ * T_SEQ;
  __shared__ float qsT[64][68];
  __shared__ float ksT[64][68];
  int tid = threadIdx.x;
  int r0 = tr * 64, c0 = tc * 64;
#pragma unroll
  for (int u = 0; u < 16; u++) {
    int idx = u * 256 + tid;
    int row = idx >> 6, d = idx & 63;
    qsT[d][row] = qsel[((size_t)(b * T_SEQ + r0 + row)) * 128 + d];
  }
#pragma unroll
  for (int u = 0; u < 16; u++) {
    int idx = u * 256 + tid;
    int c = idx >> 6, d = idx & 63;
    ksT[d][c] = kv[((size_t)(b * T_SEQ + c0 + c)) * 1024 + d];
  }
  __syncthreads();
  int tx = tid & 15, ty = tid >> 4;
  float acc[4][4] = {};
  for (int d = 0; d < 64; d++) {
    float4 qv = *(const float4*)&qsT[d][ty * 4];
    float4 kx = *(const float4*)&ksT[d][tx * 4];
    float qq[4] = {qv.x, qv.y, qv.z, qv.w};
    float kk[4] = {kx.x, kx.y, kx.z, kx.w};
#pragma unroll
    for (int i = 0; i < 4; i++)
#pragma unroll
      for (int j = 0; j < 4; j++) acc[i][j] += qq[i] * kk[j];
  }
#pragma unroll
  for (int i = 0; i < 4; i++) {
    int r = r0 + ty * 4 + i;
    uint4 o;
    int c = c0 + tx * 4;
    o.x = (c + 0 <= r) ? enc32(acc[i][0] * 0.125f) : ENC_NEGINF;
    o.y = (c + 1 <= r) ? enc32(acc[i][1] * 0.125f) : ENC_NEGINF;
    o.z = (c + 2 <= r) ? enc32(acc[i][2] * 0.125f) : ENC_NEGINF;
    o.w = (c + 3 <= r) ? enc32(acc[i][3] * 0.125f) : ENC_NEGINF;
    *(uint4*)&Sb[(size_t)r * 2048 + c] = o;
  }
}

// ---------------------------------------------------------------------------
// Selection v4, BOTH batches in one dispatch (1024 blocks; b = blk>>9).
// Wave-per-row binary-search threshold + ballot compaction; jax.lax.top_k
// tie order. Logic identical to the proven per-batch version.
// ---------------------------------------------------------------------------
__global__ __launch_bounds__(256) void select_topk_kernel(
    const unsigned* __restrict__ S,   // [2][2048][2048]
    int* __restrict__ sel_cnt, int* __restrict__ sel_idx) {
  int b = blockIdx.x >> 9;
  int blk = blockIdx.x & 511;        // 512 blocks of 4 rows per batch
  const unsigned* Sb = S + (size_t)b * T_SEQ * T_SEQ;
  int r0 = blk * 4;
  int tid = threadIdx.x;

  if (r0 < 64) {                     // rows 0..63: all causal keys selected
    for (int j = 0; j < 4; j++) {
      int r = r0 + j;
      int row = b * T_SEQ + r;
      if (tid == 0) sel_cnt[row] = r + 1;
      for (int c = tid; c <= r; c += 256) sel_idx[row * 66 + c] = c;
    }
    return;
  }

  int wv = tid >> 6, lane = tid & 63;
  int rr = r0 + wv;
  int row = b * T_SEQ + rr;
  int imax = rr >> 6;

  unsigned e[32];
  const unsigned* Sp = Sb + (size_t)rr * 2048 + lane;
#pragma unroll
  for (int i = 0; i < 32; i++) e[i] = (i <= imax) ? Sp[i * 64] : ENC_NEGINF;

  unsigned t = 0;
  for (int bit = 31; bit >= 0; --bit) {
    unsigned cand = t | (1u << bit);
    int cnt = 0;
#pragma unroll
    for (int i = 0; i < 32; i++) cnt += (e[i] >= cand) ? 1 : 0;
#pragma unroll
    for (int off = 1; off < 64; off <<= 1) cnt += __shfl_xor(cnt, off);
    if (cnt >= 64) t = cand;
  }

  unsigned long long below = (lane == 63) ? 0x7FFFFFFFFFFFFFFFull
                                          : ((1ull << lane) - 1ull);
  bool hasdiag = false;
  int base = 0;
#pragma unroll
  for (int i = 0; i < 32; i++) {
    int c = i * 64 + lane;
    bool wn = (e[i] > t);
    unsigned long long m = __ballot(wn);
    if (wn) {
      int slot = base + (int)__popcll(m & below);
      sel_idx[(size_t)row * 66 + slot] = c;
      if (c == rr) hasdiag = true;
    }
    base += (int)__popcll(m);
  }
  int g = base;
  int need = 64 - g;
  int tb = 0;
#pragma unroll
  for (int i = 0; i < 32; i++) {
    int c = i * 64 + lane;
    bool tie = (e[i] == t);
    unsigned long long m = __ballot(tie);
    int rank = tb + (int)__popcll(m & below);
    if (tie && rank < need) {
      sel_idx[(size_t)row * 66 + g + rank] = c;
      if (c == rr) hasdiag = true;
    }
    tb += (int)__popcll(m);
  }
  unsigned long long hd = __ballot(hasdiag);
  if (lane == 0) {
    sel_cnt[row] = hd ? 64 : 65;
    if (!hd) sel_idx[(size_t)row * 66 + 64] = rr;
  }
}

// ---------------------------------------------------------------------------
// Gathered attention v3 (PROVEN, round 7) — K staged ONCE per block into
// XOR-swizzled LDS; score lane=key; softmax xor-reduce; PV from global.
// Gate stays a separate kernel (round-9 fusion destroyed gw reuse: −165us).
// ---------------------------------------------------------------------------
__global__ __launch_bounds__(256) void attn_kernel(
    const float* __restrict__ q,              // [BT,2048] fp32 normed+roped
    const unsigned short* __restrict__ kvb,   // [BT,1024] bf16 normed+roped
    const int* __restrict__ sel_cnt, const int* __restrict__ sel_idx,
    float* __restrict__ yg) {
  int blk = blockIdx.x;
  int g = blk & 3;
  int br = blk >> 2;               // b*T + r
  int b = br >> 11;
  int r = br & (T_SEQ - 1);
  int tid = threadIdx.x;
  int lane = tid & 63, wv = tid >> 6;
  int H = g * 4 + wv;

  __shared__ unsigned kls[65 * 64];   // 16.6 KB, swizzled K rows
  __shared__ float pbuf[4][68];
  __shared__ int idxs[66];

  int cnt = sel_cnt[br];
  if (tid < 66) idxs[tid] = (tid < cnt) ? sel_idx[(size_t)br * 66 + tid] : 0;
  __syncthreads();

  // ---- cooperative K staging: chunk c = (row, 16B part) ----
  for (int c = tid; c < 65 * 16; c += 256) {
    int row = c >> 4, part = c & 15;
    uint4 kd = make_uint4(0u, 0u, 0u, 0u);
    if (row < cnt) {
      const unsigned short* gp = kvb
          + ((size_t)(b * T_SEQ + idxs[row])) * 1024 + g * HD + part * 8;
      kd = *(const uint4*)gp;
    }
    int slot = part ^ (row & 15);
    *(uint4*)&kls[row * 64 + slot * 4] = kd;
  }
  __syncthreads();

  // alibi slope = (2^-0.5)^(H+1), double repeated-multiply then fp32 round
  double sd = 1.0;
  for (int i = 0; i <= H; i++) sd *= 0.70710678118654752440;
  float slope = (float)sd;

  const float* qrow = q + (size_t)br * 2048 + H * HD;

  // ---- scores: key j = lane, K from swizzled LDS ----
  int kidx = idxs[min(lane, cnt - 1)];
  int swz = lane & 15;
  const unsigned* kr = &kls[lane * 64];
  float acc = 0.f;
#pragma unroll
  for (int dd = 0; dd < 16; dd++) {
    uint4 kb = *(const uint4*)&kr[(dd ^ swz) * 4];
    float4 qa = *(const float4*)(qrow + dd * 8);      // uniform broadcast
    float4 qb = *(const float4*)(qrow + dd * 8 + 4);
    acc += qa.x * bflo(kb.x) + qa.y * bfhi(kb.x);
    acc += qa.z * bflo(kb.y) + qa.w * bfhi(kb.y);
    acc += qb.x * bflo(kb.z) + qb.y * bfhi(kb.z);
    acc += qb.z * bflo(kb.w) + qb.w * bfhi(kb.w);
  }
  float sca = acc / sqrtf(128.0f);
  float tch = tanhf(sca / 30.0f) * 30.0f;
  float s = (lane < cnt) ? (tch - slope * (float)(r - kidx)) : -INFINITY;

  // ---- 65th key (row 64: swizzle key 0 -> linear): d-parallel reduce ----
  float stail = -INFINITY;
  if (cnt == 65) {
    int i64 = idxs[64];                      // uniform
    unsigned u = kls[64 * 64 + lane];        // dims 2l, 2l+1
    float2 qt = *(const float2*)(qrow + 2 * lane);
    float ta = qt.x * bflo(u) + qt.y * bfhi(u);
#pragma unroll
    for (int off = 32; off > 0; off >>= 1) ta += __shfl_xor(ta, off);
    stail = tanhf(ta / sqrtf(128.0f) / 30.0f) * 30.0f
            - slope * (float)(r - i64);
  }

  // ---- softmax (xor reductions -> all lanes) ----
  float m = s;
#pragma unroll
  for (int off = 32; off > 0; off >>= 1) m = fmaxf(m, __shfl_xor(m, off));
  m = fmaxf(m, stail);
  float e = (lane < cnt) ? expf(s - m) : 0.f;
  float sum = e;
#pragma unroll
  for (int off = 32; off > 0; off >>= 1) sum += __shfl_xor(sum, off);
  float et = (cnt == 65) ? expf(stail - m) : 0.f;
  sum += et;
  pbuf[wv][lane] = e / sum;
  if (lane == 0) pbuf[wv][64] = et / sum;
  if (lane >= 1 && lane <= 3) pbuf[wv][64 + lane] = 0.f;   // slots 65..67

  // ---- PV: lane covers dims 2l, 2l+1; V coalesced from global ----
  const unsigned short* vbase = kvb + (size_t)b * T_SEQ * 1024 + 512 + g * HD;
  float y0 = 0.f, y1 = 0.f;
  int jmax = (cnt + 3) >> 2;
  for (int j4 = 0; j4 < jmax; j4++) {
    float4 p4 = *(const float4*)&pbuf[wv][j4 * 4];
    float pp[4] = {p4.x, p4.y, p4.z, p4.w};
#pragma unroll
    for (int t = 0; t < 4; t++) {
      int ij = idxs[min(j4 * 4 + t, cnt - 1)];           // uniform
      unsigned u = *(const unsigned*)(vbase + (size_t)ij * 1024 + 2 * lane);
      y0 += pp[t] * bflo(u);
      y1 += pp[t] * bfhi(u);
    }
  }
  float2 o;
  o.x = y0;
  o.y = y1;
  *(float2*)(yg + (size_t)br * 2048 + H * HD + 2 * lane) = o;
}

// ---------------------------------------------------------------------------
// Gate v2: 32 rows/block (2048 blocks), float4 ys broadcasts. Per-output
// accumulation strictly d-ascending -> bit-identical to the proven gate.
// Reads fp32 yg, writes bf16 ygb directly.
// ---------------------------------------------------------------------------
__global__ __launch_bounds__(256) void gate_kernel(
    const float* __restrict__ yg, unsigned short* __restrict__ ygb,
    const float* __restrict__ gw, const float* __restrict__ gb) {
  int blk = blockIdx.x;              // (BT/32)*16 = 2048
  int h = blk & 15;
  int bt0 = (blk >> 4) * 32;
  int tid = threadIdx.x;
  __shared__ float ys[32][128];
  for (int i = tid; i < 32 * 128; i += 256) {
    int rr = i >> 7, d = i & 127;
    ys[rr][d] = yg[(size_t)(bt0 + rr) * 2048 + h * HD + d];
  }
  __syncthreads();
  int e = tid & 127;
  int rblk = tid >> 7;               // 0..1 -> rows rblk*16 .. +15
  const float* gwp = gw + (size_t)h * 16384 + e;
  float acc[16] = {};
  for (int d = 0; d < 128; d += 4) {
    float w0 = gwp[(size_t)(d + 0) * 128];
    float w1 = gwp[(size_t)(d + 1) * 128];
    float w2 = gwp[(size_t)(d + 2) * 128];
    float w3 = gwp[(size_t)(d + 3) * 128];
#pragma unroll
    for (int k = 0; k < 16; k++) {
      float4 y4 = *(const float4*)&ys[rblk * 16 + k][d];
      acc[k] += y4.x * w0;           // d   (ascending order preserved)
      acc[k] += y4.y * w1;           // d+1
      acc[k] += y4.z * w2;           // d+2
      acc[k] += y4.w * w3;           // d+3
    }
  }
  float bb = gb[h * 128 + e];
#pragma unroll
  for (int k = 0; k < 16; k++) {
    int rr = rblk * 16 + k;
    float gate = 1.f / (1.f + expf(-(acc[k] + bb)));
    ygb[(size_t)(bt0 + rr) * 2048 + h * HD + e] = bf16rne(ys[rr][e] * gate);
  }
}

// ---------------------------------------------------------------------------
extern "C" void kernel_launch(void* const* d_in, const int* in_sizes, int n_in,
                              void* d_out, int out_size, void* d_ws, size_t ws_size,
                              hipStream_t stream) {
  const float* x      = (const float*)d_in[0];
  const float* w_q    = (const float*)d_in[1];
  const float* b_q    = (const float*)d_in[2];
  const float* w_down = (const float*)d_in[3];
  const float* b_down = (const float*)d_in[4];
  const float* w_up   = (const float*)d_in[5];
  const float* b_up   = (const float*)d_in[6];
  const float* w_o    = (const float*)d_in[7];
  const float* b_o    = (const float*)d_in[8];
  const float* qn_w   = (const float*)d_in[9];
  const float* kn_w   = (const float*)d_in[10];
  const float* gate_w = (const float*)d_in[11];
  const float* gate_b = (const float*)d_in[12];

  // ws layout (float offsets):
  //   kvbuf 0 | yg/dlat/Sfull 4194304 (8.39M floats: dlat dead by selection;
  //   S[2][2048][2048] lives here during selection; attn overwrites with yg
  //   after select — stream-ordered) | tab 12582912 | cnt 12845056(int)
  //   sidx 12849152(int) | qsel 13120000 | [ushorts from 13906432]:
  //   xb/dlatb/ygb (8.39M ushorts) then wT region (4.19M ushorts) —
  //   wT triple-duty: w_qT -> w_upT -> kvb(bf16 kv, alive through attn)
  //   -> w_oT (written only after attn; stream-ordered).
  float* ws    = (float*)d_ws;
  float* kvbuf = ws;
  float* yg    = ws + 4194304;
  float* dlat  = yg;                          // dead before selection
  unsigned* Sfull = (unsigned*)yg;            // [2][2048][2048] during select
  float* tab   = ws + 12582912;
  int*   cnt   = (int*)(ws + 12845056);
  int*   sidx  = cnt + 4096;
  float* qsel  = ws + 13120000;               // 4096 x 128
  unsigned short* xb  = (unsigned short*)(ws + 13906432);  // 4096x2048 bf16
  unsigned short* dlatb = xb;                 // xb dead after q-proj
  unsigned short* ygb = xb;                   // dead again after up-proj
  unsigned short* wT  = xb + 8388608;         // 2048x2048 bf16 [N,K]
  unsigned short* wupT = wT;                  // w_qT dead after q-proj mfma
  unsigned short* kvb  = wT;                  // bf16 kv; wupT dead after up

  float* qbuf = (float*)d_out;                // d_out doubles as q staging
  const int BT = BATCH * T_SEQ;               // 4096

  rope_table_kernel<<<T_SEQ, 64, 0, stream>>>(tab);
  // ---- q-proj (bf16 MFMA, separate dispatch — fat1 reverted) ----
  convert_bf16_kernel<<<8192, 256, 0, stream>>>(x, xb, 2097152);
  transpose_bf16_kernel<<<dim3(64, 64), 256, 0, stream>>>(w_q, wT, 2048, 2048);
  mfma_gemm_bt<<<dim3(16, 32), 256, 0, stream>>>(xb, wT, b_q, qbuf,
                                                 BT, 2048, 2048);
  // ---- fused exact fp32 GEMM: qsel + latent down-proj (proven sgemm3) ----
  sgemm3_kernel<<<dim3(10, 64), 256, 0, stream>>>(
      x, w_q, b_q, qsel, 2048, 128, 2,
      w_down, b_down, dlat, 512, 512, 2048);
  // ---- up-proj prep ----
  convert_bf16_kernel<<<2048, 256, 0, stream>>>(dlat, dlatb, 524288);
  transpose_bf16_kernel<<<dim3(32, 16), 256, 0, stream>>>(w_up, wupT,
                                                          512, 1024);
  // ---- FAT2: kv-exact fp32 (cols 0..127) co-dispatched with up-proj MFMA
  // (cols 128..1023; disjoint writes, redundant col-block removed) ----
  fat2_kernel<<<352, 256, 0, stream>>>(dlat, w_up, b_up, kvbuf, dlatb, wupT);
  // ---- rmsnorm + rope ----
  qnorm_rope_kernel<<<BT * 4, 256, 0, stream>>>(qbuf, qn_w, tab);
  norm_rope_kernel<<<BT, 128, 0, stream>>>(qsel, qn_w, tab, 1, 128);
  kvnorm_rope_kernel<<<BT * 4, 128, 0, stream>>>(kvbuf, kn_w, tab, kvb);
  // ---- selection: both batches in single dispatches (S in yg region;
  // dlat dead here, attn overwrites yg only after select — stream-ordered) ----
  score_kernel<<<dim3(32, 32, 2), 256, 0, stream>>>(qsel, kvbuf, Sfull);
  select_topk_kernel<<<1024, 256, 0, stream>>>(Sfull, cnt, sidx);
  // ---- gathered sparse attention (bf16 K/V, K LDS-staged once/block) ----
  attn_kernel<<<BT * 4, 256, 0, stream>>>(qbuf, kvb, cnt, sidx, yg);
  // ---- gating v2 (32 rows/block, writes bf16 ygb directly) ----
  gate_kernel<<<(BT / 32) * 16, 256, 0, stream>>>(yg, ygb, gate_w, gate_b);
  // ---- o-proj (bf16 MFMA; wT overwrite is after attn in stream order) ----
  transpose_bf16_kernel<<<dim3(64, 64), 256, 0, stream>>>(w_o, wT, 2048, 2048);
  mfma_gemm_bt<<<dim3(16, 32), 256, 0, stream>>>(ygb, wT, b_o, (float*)d_out,
                                                 BT, 2048, 2048);
}

// Round 14
// 690.943 us; speedup vs baseline: 1.0442x; 1.0442x over previous
//
#include <hip/hip_runtime.h>
#include <math.h>

// Problem constants (B=2, T=2048, DIM=2048, HEADS=16, HEAD_DIM=128, N_KV=4,
// LATENT=512, SEL_TOPK=64, SEL_DIM=64, SOFTCAP=30, EPS=1e-6)
#define T_SEQ 2048
#define BATCH 2
#define NHEADS 16
#define HD 128
#define NKV 4

typedef __bf16 bf16x8 __attribute__((ext_vector_type(8)));
typedef float f32x4 __attribute__((ext_vector_type(4)));

__device__ inline unsigned short bf16rne(float f) {
  unsigned u = __float_as_uint(f);
  unsigned r = (u + 0x7FFFu + ((u >> 16) & 1u)) >> 16;
  return (unsigned short)r;
}

__device__ inline float bflo(unsigned u) {          // low bf16 of a dword
  return __uint_as_float(u << 16);
}
__device__ inline float bfhi(unsigned u) {          // high bf16 of a dword
  return __uint_as_float(u & 0xFFFF0000u);
}

__device__ inline void gload_lds16(const void* g, void* l) {
  __builtin_amdgcn_global_load_lds(
      (__attribute__((address_space(1))) void*)const_cast<void*>(g),
      (__attribute__((address_space(3))) void*)l, 16, 0, 0);
}

// monotonic encoding: enc(a) < enc(b) <=> a < b (floats, -inf ok)
#define ENC_NEGINF 0x007FFFFFu
__device__ inline unsigned enc32(float v) {
  unsigned u = __float_as_uint(v);
  return (u & 0x80000000u) ? ~u : (u | 0x80000000u);
}

// ---------------------------------------------------------------------------
// RoPE table: tab[t][i] = (cos, sin), i = pair index 0..63. numpy fp32 op
// order: y=fl32(10000^x) (double pow), inv=1/y (fp32), angle=fl32(t*inv).
// ---------------------------------------------------------------------------
__global__ void rope_table_kernel(float* __restrict__ tab) {
  int t = blockIdx.x;
  int i = threadIdx.x;                 // 0..63
  int j = (2 * i) & 63;
  float y = (float)pow(10000.0, (double)j / 64.0);
  float invf = 1.0f / y;
  float angle = (float)t * invf;
  double a = (double)angle;
  tab[(t * 64 + i) * 2 + 0] = (float)cos(a);
  tab[(t * 64 + i) * 2 + 1] = (float)sin(a);
}

// ---------------------------------------------------------------------------
// RMSNorm (128 dims) + interleaved RoPE, in place. EXACT variant (LDS-tree
// reduction order frozen — feeds the selection-exact path). qsel only.
// ---------------------------------------------------------------------------
__global__ __launch_bounds__(128) void norm_rope_kernel(
    float* __restrict__ base, const float* __restrict__ w,
    const float* __restrict__ tab, int Hloc, int rowStride) {
  int blk = blockIdx.x;
  int h = blk % Hloc;
  int bt = blk / Hloc;
  int t = bt & (T_SEQ - 1);
  float* row = base + (size_t)bt * rowStride + h * HD;
  int d = threadIdx.x;
  float v = row[d];
  __shared__ float red[128];
  red[d] = v * v;
  __syncthreads();
#pragma unroll
  for (int off = 64; off > 0; off >>= 1) {
    if (d < off) red[d] += red[d + off];
    __syncthreads();
  }
  float ssum = red[0];
  __syncthreads();
  float inv = 1.0f / sqrtf(ssum / 128.0f + 1e-6f);
  float xn = v * inv * w[d];
  red[d] = xn;
  __syncthreads();
  int p = d >> 1;
  float c  = tab[(t * 64 + p) * 2 + 0];
  float sn = tab[(t * 64 + p) * 2 + 1];
  float x1 = red[p * 2], x2 = red[p * 2 + 1];
  row[d] = ((d & 1) == 0) ? (x1 * c - x2 * sn) : (x1 * sn + x2 * c);
}

// ---------------------------------------------------------------------------
// kv RMSNorm+RoPE: EXACT fp32 path identical to norm_rope_kernel (Hloc=4,
// rowStride=1024), plus pure epilogue: bf16 of the normed k slice AND bf16
// convert of the matching raw V slice into kvb. Kills the separate convert.
// ---------------------------------------------------------------------------
__global__ __launch_bounds__(128) void kvnorm_rope_kernel(
    float* __restrict__ base, const float* __restrict__ w,
    const float* __restrict__ tab, unsigned short* __restrict__ kvb) {
  int blk = blockIdx.x;              // bt*4 + h
  int h = blk % 4;
  int bt = blk / 4;
  int t = bt & (T_SEQ - 1);
  float* row = base + (size_t)bt * 1024 + h * HD;
  int d = threadIdx.x;
  float v = row[d];
  __shared__ float red[128];
  red[d] = v * v;
  __syncthreads();
#pragma unroll
  for (int off = 64; off > 0; off >>= 1) {
    if (d < off) red[d] += red[d + off];
    __syncthreads();
  }
  float ssum = red[0];
  __syncthreads();
  float inv = 1.0f / sqrtf(ssum / 128.0f + 1e-6f);
  float xn = v * inv * w[d];
  red[d] = xn;
  __syncthreads();
  int p = d >> 1;
  float c  = tab[(t * 64 + p) * 2 + 0];
  float sn = tab[(t * 64 + p) * 2 + 1];
  float x1 = red[p * 2], x2 = red[p * 2 + 1];
  float out = ((d & 1) == 0) ? (x1 * c - x2 * sn) : (x1 * sn + x2 * c);
  row[d] = out;
  size_t kb = (size_t)bt * 1024 + h * HD + d;
  kvb[kb] = bf16rne(out);
  float vv = base[(size_t)bt * 1024 + 512 + h * HD + d];   // raw V slice
  kvb[(size_t)bt * 1024 + 512 + h * HD + d] = bf16rne(vv);
}

// ---------------------------------------------------------------------------
// q RMSNorm+RoPE: wave-per-row, shuffle reduce, no LDS/barriers. q feeds
// only the tanh/softmax attention path (bf16-tolerant) — reduction-order
// change is safe here (NOT used for selection).
// ---------------------------------------------------------------------------
__global__ __launch_bounds__(256) void qnorm_rope_kernel(
    float* __restrict__ base, const float* __restrict__ w,
    const float* __restrict__ tab) {
  int row = blockIdx.x * 4 + (threadIdx.x >> 6);   // over BT*16 rows
  int lane = threadIdx.x & 63;
  int h = row & 15;
  int bt = row >> 4;
  int t = bt & (T_SEQ - 1);
  float* rp = base + (size_t)bt * 2048 + h * HD;
  float2 v = *(const float2*)(rp + 2 * lane);
  float ss = v.x * v.x + v.y * v.y;
#pragma unroll
  for (int off = 32; off > 0; off >>= 1) ss += __shfl_xor(ss, off);
  float inv = 1.0f / sqrtf(ss / 128.0f + 1e-6f);
  float2 wv = *(const float2*)(w + 2 * lane);
  float x1 = v.x * inv * wv.x;
  float x2 = v.y * inv * wv.y;
  float2 cs = *(const float2*)(tab + (t * 64 + lane) * 2);
  float2 o;
  o.x = x1 * cs.x - x2 * cs.y;
  o.y = x1 * cs.y + x2 * cs.x;
  *(float2*)(rp + 2 * lane) = o;
}

// ---------------------------------------------------------------------------
// fp32 GEMM body (PROVEN sgemm3 shape: 64x64 tile, BK=16, 256 threads, 4x4
// microtile, register prefetch). Per-output summation order IDENTICAL:
// k sequential 0..K-1, acc[i][j] += a[i]*b[j] (selection-exactness frozen).
// Block mapping resolved by the CALLER.
// ---------------------------------------------------------------------------
#define BKG 16
__device__ __forceinline__ void sgemm_body(
    const float* __restrict__ A, const float* __restrict__ W,
    const float* __restrict__ bias, float* __restrict__ C,
    int ldw, int ldc, int n0, int m0, int K, char* smem) {
  float (*As)[68] = (float (*)[68])smem;               // 16*68*4 = 4352 B
  float (*Bs)[68] = (float (*)[68])(smem + 4352);      // 4352 B
  int tid = threadIdx.x;
  int tx = tid & 15;
  int ty = tid >> 4;
  int ar = tid >> 2, ac = (tid & 3) * 4;
  int brr = tid >> 4, bc = (tid & 15) * 4;
  const float* Ap = A + (size_t)(m0 + ar) * K + ac;
  const float* Wp = W + (size_t)brr * ldw + n0 + bc;
  float acc[4][4] = {};
  // prologue: stage tile k0=0 into registers
  float4 av = *(const float4*)(Ap);
  float4 wv = *(const float4*)(Wp);
  for (int k0 = 0; k0 < K; k0 += BKG) {
    As[ac + 0][ar] = av.x; As[ac + 1][ar] = av.y;
    As[ac + 2][ar] = av.z; As[ac + 3][ar] = av.w;
    *(float4*)&Bs[brr][bc] = wv;
    __syncthreads();
    if (k0 + BKG < K) {               // prefetch next tile under compute
      av = *(const float4*)(Ap + k0 + BKG);
      wv = *(const float4*)(Wp + (size_t)(k0 + BKG) * ldw);
    }
#pragma unroll
    for (int kk = 0; kk < BKG; kk++) {
      float4 a = *(const float4*)&As[kk][ty * 4];
      float4 b = *(const float4*)&Bs[kk][tx * 4];
      float aa[4] = {a.x, a.y, a.z, a.w};
      float bb[4] = {b.x, b.y, b.z, b.w};
#pragma unroll
      for (int i = 0; i < 4; i++)
#pragma unroll
        for (int j = 0; j < 4; j++) acc[i][j] += aa[i] * bb[j];
    }
    __syncthreads();
  }
  float4 bv = *(const float4*)&bias[n0 + tx * 4];
  float bb[4] = {bv.x, bv.y, bv.z, bv.w};
#pragma unroll
  for (int i = 0; i < 4; i++) {
    float4 o;
    o.x = acc[i][0] + bb[0];
    o.y = acc[i][1] + bb[1];
    o.z = acc[i][2] + bb[2];
    o.w = acc[i][3] + bb[3];
    *(float4*)&C[(size_t)(m0 + ty * 4 + i) * ldc + n0 + tx * 4] = o;
  }
}

// ---------------------------------------------------------------------------
// bf16 MFMA GEMM body: C[M,N] = A[M,K] @ BT[N,K]^T + bias, fp32 accumulate.
// 128x128 tile, BK=64, 4 waves, 16x16x32 MFMA, fragment-major LDS via
// global_load_lds(16B). Block mapping resolved by the caller.
// ---------------------------------------------------------------------------
__device__ __forceinline__ void mfma_body(
    const unsigned short* __restrict__ A,   // [M,K] bf16
    const unsigned short* __restrict__ BT,  // [N,K] bf16
    const float* __restrict__ bias,         // [N]
    float* __restrict__ C,                  // [M,N] fp32
    int N, int K, int m0, int n0, char* smem) {
  bf16x8 (*lA)[64] = (bf16x8 (*)[64])smem;             // 16 KB
  bf16x8 (*lB)[64] = (bf16x8 (*)[64])(smem + 16384);   // 16 KB
  int tid = threadIdx.x;
  int w = tid >> 6, lane = tid & 63;
  int wm = w >> 1, wn = w & 1;
  f32x4 acc[4][4] = {};
  int sr = lane & 15;
  int sk = (lane >> 4) * 8;
  const unsigned short* Abase = A + (size_t)(m0 + sr) * K + sk;
  const unsigned short* Bbase = BT + (size_t)(n0 + sr) * K + sk;

  for (int k0 = 0; k0 < K; k0 += 64) {
    __syncthreads();
#pragma unroll
    for (int c = 0; c < 4; c++) {
      int ch = w * 4 + c;
      int tt = ch >> 1, kk = ch & 1;
      gload_lds16(Abase + (size_t)(tt * 16) * K + k0 + kk * 32, &lA[ch][0]);
      gload_lds16(Bbase + (size_t)(tt * 16) * K + k0 + kk * 32, &lB[ch][0]);
    }
    __syncthreads();
#pragma unroll
    for (int kk = 0; kk < 2; kk++) {
      bf16x8 af[4], bfr[4];
#pragma unroll
      for (int t = 0; t < 4; t++) {
        af[t]  = lA[(wm * 4 + t) * 2 + kk][lane];
        bfr[t] = lB[(wn * 4 + t) * 2 + kk][lane];
      }
#pragma unroll
      for (int i = 0; i < 4; i++)
#pragma unroll
        for (int j = 0; j < 4; j++)
          acc[i][j] = __builtin_amdgcn_mfma_f32_16x16x32_bf16(
              af[i], bfr[j], acc[i][j], 0, 0, 0);
    }
  }
  int col0 = n0 + wn * 64 + (lane & 15);
  int row0 = m0 + wm * 64 + (lane >> 4) * 4;
#pragma unroll
  for (int j = 0; j < 4; j++) {
    float bv = bias[col0 + j * 16];
#pragma unroll
    for (int i = 0; i < 4; i++) {
#pragma unroll
      for (int r = 0; r < 4; r++)
        C[(size_t)(row0 + i * 16 + r) * N + col0 + j * 16] = acc[i][j][r] + bv;
    }
  }
}

// ---------------------------------------------------------------------------
// Standalone MFMA GEMM (o-proj): XCD-aware swizzle (grid multiple of 8).
// ---------------------------------------------------------------------------
__global__ __launch_bounds__(256) void mfma_gemm_bt(
    const unsigned short* __restrict__ A,
    const unsigned short* __restrict__ BT,
    const float* __restrict__ bias, float* __restrict__ C,
    int M, int N, int K) {
  __shared__ __align__(16) char smem[32768];
  int nb = gridDim.x * gridDim.y;
  int bid = blockIdx.y * gridDim.x + blockIdx.x;
  int cpx = nb >> 3;
  int sw = (bid & 7) * cpx + (bid >> 3);
  int bxs = sw % gridDim.x;
  int bys = sw / gridDim.x;
  mfma_body(A, BT, bias, C, N, K, bys * 128, bxs * 128, smem);
}

// ---------------------------------------------------------------------------
// FAT kernel 1 (RESTORED — round 12 measured best total 715.8 vs 721.5
// without; the 222us revert threshold was based on a mis-estimated
// sequential baseline). NEW: XCD-chunked swizzle in BOTH ranges — hardware
// dispatches consecutive bids round-robin over 8 XCDs, so map bid&7 to a
// contiguous logical chunk: the 10 same-row sgemm blocks become L2-local
// (A-panel footprint 8 row-groups x 512KB = 4MB = one XCD L2).
// ---------------------------------------------------------------------------
__global__ __launch_bounds__(256) void fat1_kernel(
    const float* __restrict__ x,
    const float* __restrict__ w_q, const float* __restrict__ b_q,
    float* __restrict__ qsel,
    const float* __restrict__ w_down, const float* __restrict__ b_down,
    float* __restrict__ dlat,
    const unsigned short* __restrict__ xb,
    const unsigned short* __restrict__ wT,
    float* __restrict__ qbuf) {
  __shared__ __align__(16) char smem[32768];
  int bid = blockIdx.x;
  if (bid < 640) {                    // fp32 exact GEMM (dual-source)
    int sw = (bid & 7) * 80 + (bid >> 3);   // 80 blocks per XCD, bijective
    int bx = sw % 10, by = sw / 10;
    if (bx < 2)
      sgemm_body(x, w_q, b_q, qsel, 2048, 128, bx * 64, by * 64, 2048, smem);
    else
      sgemm_body(x, w_down, b_down, dlat, 512, 512, (bx - 2) * 64, by * 64,
                 2048, smem);
  } else {                            // q-proj MFMA: M=4096,N=2048,K=2048
    int mb = bid - 640;               // 0..511
    int sw = (mb & 7) * 64 + (mb >> 3);     // 64 blocks per XCD, bijective
    int bx = sw & 15, by = sw >> 4;
    mfma_body(xb, wT, b_q, qbuf, 2048, 2048, by * 128, bx * 128, smem);
  }
}

// ---------------------------------------------------------------------------
// FAT kernel 2 (PROVEN): co-dispatch [kv-exact fp32 sgemm cols 0..127, 128
// blocks] with [up-proj bf16 MFMA cols 128..1023, 224 blocks]. Column
// ranges DISJOINT (mfma col-block 0 removed — redundant work). Same final
// kvbuf contents.
// ---------------------------------------------------------------------------
__global__ __launch_bounds__(256) void fat2_kernel(
    const float* __restrict__ dlat,
    const float* __restrict__ w_up, const float* __restrict__ b_up,
    float* __restrict__ kvbuf,
    const unsigned short* __restrict__ dlatb,
    const unsigned short* __restrict__ wupT) {
  __shared__ __align__(16) char smem[32768];
  int bid = blockIdx.x;
  if (bid < 128) {                    // exact fp32: cols 0..127, K=512
    int bx = bid & 1, by = bid >> 1;
    sgemm_body(dlat, w_up, b_up, kvbuf, 1024, 1024, bx * 64, by * 64, 512,
               smem);
  } else {                            // up-proj MFMA: col-blocks 1..7
    int mb = bid - 128;               // 0..223
    int bx = mb % 7, by = mb / 7;
    mfma_body(dlatb, wupT, b_up, kvbuf, 1024, 512, by * 128, (bx + 1) * 128,
              smem);
  }
}

// ---------------------------------------------------------------------------
// fp32 -> bf16 flat convert (RNE), 4 elems/thread.
// ---------------------------------------------------------------------------
__global__ __launch_bounds__(256) void convert_bf16_kernel(
    const float* __restrict__ X, unsigned short* __restrict__ Y, int n4) {
  int i = blockIdx.x * 256 + threadIdx.x;
  if (i >= n4) return;
  float4 v = ((const float4*)X)[i];
  ushort4 o;
  o.x = bf16rne(v.x); o.y = bf16rne(v.y);
  o.z = bf16rne(v.z); o.w = bf16rne(v.w);
  ((ushort4*)Y)[i] = o;
}

// ---------------------------------------------------------------------------
// fp32 [K,N] -> bf16 [N,K] transpose-convert, 32x32 LDS tile.
// ---------------------------------------------------------------------------
__global__ __launch_bounds__(256) void transpose_bf16_kernel(
    const float* __restrict__ W, unsigned short* __restrict__ WT,
    int K, int N) {
  __shared__ unsigned short t[32][33];
  int k0 = blockIdx.y * 32, n0 = blockIdx.x * 32;
  int tid = threadIdx.x;
#pragma unroll
  for (int i = 0; i < 4; i++) {
    int idx = tid + i * 256;
    int r = idx >> 5, c = idx & 31;
    t[c][r] = bf16rne(W[(size_t)(k0 + r) * N + n0 + c]);
  }
  __syncthreads();
#pragma unroll
  for (int i = 0; i < 4; i++) {
    int idx = tid + i * 256;
    int r = idx >> 5, c = idx & 31;
    WT[(size_t)(n0 + r) * K + k0 + c] = t[r][c];
  }
}

// ---------------------------------------------------------------------------
// Selection scores, BOTH batches in one dispatch (blockIdx.z = b).
// One 64x64 causal tile per block.
// S[b][r][c] = enc32( (q[r,0:64] . k[c,0:64]) * 0.125 ) for c<=r else NEGINF.
// ---------------------------------------------------------------------------
__global__ __launch_bounds__(256) void score_kernel(
    const float* __restrict__ qsel,   // [BT,128] (normed+roped head 0)
    const float* __restrict__ kv,     // [BT,1024] (post-norm; k head0 = 0:64)
    unsigned* __restrict__ S) {       // [2][2048][2048]
  int tc = blockIdx.x, tr = blockIdx.y;
  int b = blockIdx.z;
  if (tc > tr || tr == 0) return;     // causal; rows 0..63 use early path
  unsigned* Sb = S + (size_t)b * T_SEQ * T_SEQ;
  __shared__ float qsT[64][68];
  __shared__ float ksT[64][68];
  int tid = threadIdx.x;
  int r0 = tr * 64, c0 = tc * 64;
#pragma unroll
  for (int u = 0; u < 16; u++) {
    int idx = u * 256 + tid;
    int row = idx >> 6, d = idx & 63;
    qsT[d][row] = qsel[((size_t)(b * T_SEQ + r0 + row)) * 128 + d];
  }
#pragma unroll
  for (int u = 0; u < 16; u++) {
    int idx = u * 256 + tid;
    int c = idx >> 6, d = idx & 63;
    ksT[d][c] = kv[((size_t)(b * T_SEQ + c0 + c)) * 1024 + d];
  }
  __syncthreads();
  int tx = tid & 15, ty = tid >> 4;
  float acc[4][4] = {};
  for (int d = 0; d < 64; d++) {
    float4 qv = *(const float4*)&qsT[d][ty * 4];
    float4 kx = *(const float4*)&ksT[d][tx * 4];
    float qq[4] = {qv.x, qv.y, qv.z, qv.w};
    float kk[4] = {kx.x, kx.y, kx.z, kx.w};
#pragma unroll
    for (int i = 0; i < 4; i++)
#pragma unroll
      for (int j = 0; j < 4; j++) acc[i][j] += qq[i] * kk[j];
  }
#pragma unroll
  for (int i = 0; i < 4; i++) {
    int r = r0 + ty * 4 + i;
    uint4 o;
    int c = c0 + tx * 4;
    o.x = (c + 0 <= r) ? enc32(acc[i][0] * 0.125f) : ENC_NEGINF;
    o.y = (c + 1 <= r) ? enc32(acc[i][1] * 0.125f) : ENC_NEGINF;
    o.z = (c + 2 <= r) ? enc32(acc[i][2] * 0.125f) : ENC_NEGINF;
    o.w = (c + 3 <= r) ? enc32(acc[i][3] * 0.125f) : ENC_NEGINF;
    *(uint4*)&Sb[(size_t)r * 2048 + c] = o;
  }
}

// ---------------------------------------------------------------------------
// Selection v4, BOTH batches in one dispatch (1024 blocks; b = blk>>9).
// Wave-per-row binary-search threshold + ballot compaction; jax.lax.top_k
// tie order. Logic identical to the proven per-batch version.
// ---------------------------------------------------------------------------
__global__ __launch_bounds__(256) void select_topk_kernel(
    const unsigned* __restrict__ S,   // [2][2048][2048]
    int* __restrict__ sel_cnt, int* __restrict__ sel_idx) {
  int b = blockIdx.x >> 9;
  int blk = blockIdx.x & 511;        // 512 blocks of 4 rows per batch
  const unsigned* Sb = S + (size_t)b * T_SEQ * T_SEQ;
  int r0 = blk * 4;
  int tid = threadIdx.x;

  if (r0 < 64) {                     // rows 0..63: all causal keys selected
    for (int j = 0; j < 4; j++) {
      int r = r0 + j;
      int row = b * T_SEQ + r;
      if (tid == 0) sel_cnt[row] = r + 1;
      for (int c = tid; c <= r; c += 256) sel_idx[row * 66 + c] = c;
    }
    return;
  }

  int wv = tid >> 6, lane = tid & 63;
  int rr = r0 + wv;
  int row = b * T_SEQ + rr;
  int imax = rr >> 6;

  unsigned e[32];
  const unsigned* Sp = Sb + (size_t)rr * 2048 + lane;
#pragma unroll
  for (int i = 0; i < 32; i++) e[i] = (i <= imax) ? Sp[i * 64] : ENC_NEGINF;

  unsigned t = 0;
  for (int bit = 31; bit >= 0; --bit) {
    unsigned cand = t | (1u << bit);
    int cnt = 0;
#pragma unroll
    for (int i = 0; i < 32; i++) cnt += (e[i] >= cand) ? 1 : 0;
#pragma unroll
    for (int off = 1; off < 64; off <<= 1) cnt += __shfl_xor(cnt, off);
    if (cnt >= 64) t = cand;
  }

  unsigned long long below = (lane == 63) ? 0x7FFFFFFFFFFFFFFFull
                                          : ((1ull << lane) - 1ull);
  bool hasdiag = false;
  int base = 0;
#pragma unroll
  for (int i = 0; i < 32; i++) {
    int c = i * 64 + lane;
    bool wn = (e[i] > t);
    unsigned long long m = __ballot(wn);
    if (wn) {
      int slot = base + (int)__popcll(m & below);
      sel_idx[(size_t)row * 66 + slot] = c;
      if (c == rr) hasdiag = true;
    }
    base += (int)__popcll(m);
  }
  int g = base;
  int need = 64 - g;
  int tb = 0;
#pragma unroll
  for (int i = 0; i < 32; i++) {
    int c = i * 64 + lane;
    bool tie = (e[i] == t);
    unsigned long long m = __ballot(tie);
    int rank = tb + (int)__popcll(m & below);
    if (tie && rank < need) {
      sel_idx[(size_t)row * 66 + g + rank] = c;
      if (c == rr) hasdiag = true;
    }
    tb += (int)__popcll(m);
  }
  unsigned long long hd = __ballot(hasdiag);
  if (lane == 0) {
    sel_cnt[row] = hd ? 64 : 65;
    if (!hd) sel_idx[(size_t)row * 66 + 64] = rr;
  }
}

// ---------------------------------------------------------------------------
// Gathered attention v3 (PROVEN, round 7) — K staged ONCE per block into
// XOR-swizzled LDS; score lane=key; softmax xor-reduce; PV from global.
// Gate stays a separate kernel (round-9 fusion destroyed gw reuse: −165us).
// ---------------------------------------------------------------------------
__global__ __launch_bounds__(256) void attn_kernel(
    const float* __restrict__ q,              // [BT,2048] fp32 normed+roped
    const unsigned short* __restrict__ kvb,   // [BT,1024] bf16 normed+roped
    const int* __restrict__ sel_cnt, const int* __restrict__ sel_idx,
    float* __restrict__ yg) {
  int blk = blockIdx.x;
  int g = blk & 3;
  int br = blk >> 2;               // b*T + r
  int b = br >> 11;
  int r = br & (T_SEQ - 1);
  int tid = threadIdx.x;
  int lane = tid & 63, wv = tid >> 6;
  int H = g * 4 + wv;

  __shared__ unsigned kls[65 * 64];   // 16.6 KB, swizzled K rows
  __shared__ float pbuf[4][68];
  __shared__ int idxs[66];

  int cnt = sel_cnt[br];
  if (tid < 66) idxs[tid] = (tid < cnt) ? sel_idx[(size_t)br * 66 + tid] : 0;
  __syncthreads();

  // ---- cooperative K staging: chunk c = (row, 16B part) ----
  for (int c = tid; c < 65 * 16; c += 256) {
    int row = c >> 4, part = c & 15;
    uint4 kd = make_uint4(0u, 0u, 0u, 0u);
    if (row < cnt) {
      const unsigned short* gp = kvb
          + ((size_t)(b * T_SEQ + idxs[row])) * 1024 + g * HD + part * 8;
      kd = *(const uint4*)gp;
    }
    int slot = part ^ (row & 15);
    *(uint4*)&kls[row * 64 + slot * 4] = kd;
  }
  __syncthreads();

  // alibi slope = (2^-0.5)^(H+1), double repeated-multiply then fp32 round
  double sd = 1.0;
  for (int i = 0; i <= H; i++) sd *= 0.70710678118654752440;
  float slope = (float)sd;

  const float* qrow = q + (size_t)br * 2048 + H * HD;

  // ---- scores: key j = lane, K from swizzled LDS ----
  int kidx = idxs[min(lane, cnt - 1)];
  int swz = lane & 15;
  const unsigned* kr = &kls[lane * 64];
  float acc = 0.f;
#pragma unroll
  for (int dd = 0; dd < 16; dd++) {
    uint4 kb = *(const uint4*)&kr[(dd ^ swz) * 4];
    float4 qa = *(const float4*)(qrow + dd * 8);      // uniform broadcast
    float4 qb = *(const float4*)(qrow + dd * 8 + 4);
    acc += qa.x * bflo(kb.x) + qa.y * bfhi(kb.x);
    acc += qa.z * bflo(kb.y) + qa.w * bfhi(kb.y);
    acc += qb.x * bflo(kb.z) + qb.y * bfhi(kb.z);
    acc += qb.z * bflo(kb.w) + qb.w * bfhi(kb.w);
  }
  float sca = acc / sqrtf(128.0f);
  float tch = tanhf(sca / 30.0f) * 30.0f;
  float s = (lane < cnt) ? (tch - slope * (float)(r - kidx)) : -INFINITY;

  // ---- 65th key (row 64: swizzle key 0 -> linear): d-parallel reduce ----
  float stail = -INFINITY;
  if (cnt == 65) {
    int i64 = idxs[64];                      // uniform
    unsigned u = kls[64 * 64 + lane];        // dims 2l, 2l+1
    float2 qt = *(const float2*)(qrow + 2 * lane);
    float ta = qt.x * bflo(u) + qt.y * bfhi(u);
#pragma unroll
    for (int off = 32; off > 0; off >>= 1) ta += __shfl_xor(ta, off);
    stail = tanhf(ta / sqrtf(128.0f) / 30.0f) * 30.0f
            - slope * (float)(r - i64);
  }

  // ---- softmax (xor reductions -> all lanes) ----
  float m = s;
#pragma unroll
  for (int off = 32; off > 0; off >>= 1) m = fmaxf(m, __shfl_xor(m, off));
  m = fmaxf(m, stail);
  float e = (lane < cnt) ? expf(s - m) : 0.f;
  float sum = e;
#pragma unroll
  for (int off = 32; off > 0; off >>= 1) sum += __shfl_xor(sum, off);
  float et = (cnt == 65) ? expf(stail - m) : 0.f;
  sum += et;
  pbuf[wv][lane] = e / sum;
  if (lane == 0) pbuf[wv][64] = et / sum;
  if (lane >= 1 && lane <= 3) pbuf[wv][64 + lane] = 0.f;   // slots 65..67

  // ---- PV: lane covers dims 2l, 2l+1; V coalesced from global ----
  const unsigned short* vbase = kvb + (size_t)b * T_SEQ * 1024 + 512 + g * HD;
  float y0 = 0.f, y1 = 0.f;
  int jmax = (cnt + 3) >> 2;
  for (int j4 = 0; j4 < jmax; j4++) {
    float4 p4 = *(const float4*)&pbuf[wv][j4 * 4];
    float pp[4] = {p4.x, p4.y, p4.z, p4.w};
#pragma unroll
    for (int t = 0; t < 4; t++) {
      int ij = idxs[min(j4 * 4 + t, cnt - 1)];           // uniform
      unsigned u = *(const unsigned*)(vbase + (size_t)ij * 1024 + 2 * lane);
      y0 += pp[t] * bflo(u);
      y1 += pp[t] * bfhi(u);
    }
  }
  float2 o;
  o.x = y0;
  o.y = y1;
  *(float2*)(yg + (size_t)br * 2048 + H * HD + 2 * lane) = o;
}

// ---------------------------------------------------------------------------
// Gate v2: 32 rows/block (2048 blocks), float4 ys broadcasts. Per-output
// accumulation strictly d-ascending -> bit-identical to the proven gate.
// Reads fp32 yg, writes bf16 ygb directly.
// ---------------------------------------------------------------------------
__global__ __launch_bounds__(256) void gate_kernel(
    const float* __restrict__ yg, unsigned short* __restrict__ ygb,
    const float* __restrict__ gw, const float* __restrict__ gb) {
  int blk = blockIdx.x;              // (BT/32)*16 = 2048
  int h = blk & 15;
  int bt0 = (blk >> 4) * 32;
  int tid = threadIdx.x;
  __shared__ float ys[32][128];
  for (int i = tid; i < 32 * 128; i += 256) {
    int rr = i >> 7, d = i & 127;
    ys[rr][d] = yg[(size_t)(bt0 + rr) * 2048 + h * HD + d];
  }
  __syncthreads();
  int e = tid & 127;
  int rblk = tid >> 7;               // 0..1 -> rows rblk*16 .. +15
  const float* gwp = gw + (size_t)h * 16384 + e;
  float acc[16] = {};
  for (int d = 0; d < 128; d += 4) {
    float w0 = gwp[(size_t)(d + 0) * 128];
    float w1 = gwp[(size_t)(d + 1) * 128];
    float w2 = gwp[(size_t)(d + 2) * 128];
    float w3 = gwp[(size_t)(d + 3) * 128];
#pragma unroll
    for (int k = 0; k < 16; k++) {
      float4 y4 = *(const float4*)&ys[rblk * 16 + k][d];
      acc[k] += y4.x * w0;           // d   (ascending order preserved)
      acc[k] += y4.y * w1;           // d+1
      acc[k] += y4.z * w2;           // d+2
      acc[k] += y4.w * w3;           // d+3
    }
  }
  float bb = gb[h * 128 + e];
#pragma unroll
  for (int k = 0; k < 16; k++) {
    int rr = rblk * 16 + k;
    float gate = 1.f / (1.f + expf(-(acc[k] + bb)));
    ygb[(size_t)(bt0 + rr) * 2048 + h * HD + e] = bf16rne(ys[rr][e] * gate);
  }
}

// ---------------------------------------------------------------------------
extern "C" void kernel_launch(void* const* d_in, const int* in_sizes, int n_in,
                              void* d_out, int out_size, void* d_ws, size_t ws_size,
                              hipStream_t stream) {
  const float* x      = (const float*)d_in[0];
  const float* w_q    = (const float*)d_in[1];
  const float* b_q    = (const float*)d_in[2];
  const float* w_down = (const float*)d_in[3];
  const float* b_down = (const float*)d_in[4];
  const float* w_up   = (const float*)d_in[5];
  const float* b_up   = (const float*)d_in[6];
  const float* w_o    = (const float*)d_in[7];
  const float* b_o    = (const float*)d_in[8];
  const float* qn_w   = (const float*)d_in[9];
  const float* kn_w   = (const float*)d_in[10];
  const float* gate_w = (const float*)d_in[11];
  const float* gate_b = (const float*)d_in[12];

  // ws layout (float offsets):
  //   kvbuf 0 | yg/dlat/Sfull 4194304 (8.39M floats: dlat dead by selection;
  //   S[2][2048][2048] lives here during selection; attn overwrites with yg
  //   after select — stream-ordered) | tab 12582912 | cnt 12845056(int)
  //   sidx 12849152(int) | qsel 13120000 | [ushorts from 13906432]:
  //   xb/dlatb/ygb (8.39M ushorts) then wT region (4.19M ushorts) —
  //   wT triple-duty: w_qT -> w_upT -> kvb(bf16 kv, alive through attn)
  //   -> w_oT (written only after attn; stream-ordered).
  float* ws    = (float*)d_ws;
  float* kvbuf = ws;
  float* yg    = ws + 4194304;
  float* dlat  = yg;                          // dead before selection
  unsigned* Sfull = (unsigned*)yg;            // [2][2048][2048] during select
  float* tab   = ws + 12582912;
  int*   cnt   = (int*)(ws + 12845056);
  int*   sidx  = cnt + 4096;
  float* qsel  = ws + 13120000;               // 4096 x 128
  unsigned short* xb  = (unsigned short*)(ws + 13906432);  // 4096x2048 bf16
  unsigned short* dlatb = xb;                 // xb dead after q-proj
  unsigned short* ygb = xb;                   // dead again after up-proj
  unsigned short* wT  = xb + 8388608;         // 2048x2048 bf16 [N,K]
  unsigned short* wupT = wT;                  // w_qT dead after q-proj mfma
  unsigned short* kvb  = wT;                  // bf16 kv; wupT dead after up

  float* qbuf = (float*)d_out;                // d_out doubles as q staging
  const int BT = BATCH * T_SEQ;               // 4096

  rope_table_kernel<<<T_SEQ, 64, 0, stream>>>(tab);
  // ---- q-proj prep ----
  convert_bf16_kernel<<<8192, 256, 0, stream>>>(x, xb, 2097152);
  transpose_bf16_kernel<<<dim3(64, 64), 256, 0, stream>>>(w_q, wT, 2048, 2048);
  // ---- FAT1: exact fp32 GEMM (qsel+dlat, XCD-chunked) co-dispatched with
  // q-proj MFMA (XCD-chunked) ----
  fat1_kernel<<<1152, 256, 0, stream>>>(x, w_q, b_q, qsel,
                                        w_down, b_down, dlat,
                                        xb, wT, qbuf);
  // ---- up-proj prep ----
  convert_bf16_kernel<<<2048, 256, 0, stream>>>(dlat, dlatb, 524288);
  transpose_bf16_kernel<<<dim3(32, 16), 256, 0, stream>>>(w_up, wupT,
                                                          512, 1024);
  // ---- FAT2: kv-exact fp32 (cols 0..127) co-dispatched with up-proj MFMA
  // (cols 128..1023; disjoint writes, redundant col-block removed) ----
  fat2_kernel<<<352, 256, 0, stream>>>(dlat, w_up, b_up, kvbuf, dlatb, wupT);
  // ---- rmsnorm + rope ----
  qnorm_rope_kernel<<<BT * 4, 256, 0, stream>>>(qbuf, qn_w, tab);
  norm_rope_kernel<<<BT, 128, 0, stream>>>(qsel, qn_w, tab, 1, 128);
  kvnorm_rope_kernel<<<BT * 4, 128, 0, stream>>>(kvbuf, kn_w, tab, kvb);
  // ---- selection: both batches in single dispatches (S in yg region;
  // dlat dead here, attn overwrites yg only after select — stream-ordered) ----
  score_kernel<<<dim3(32, 32, 2), 256, 0, stream>>>(qsel, kvbuf, Sfull);
  select_topk_kernel<<<1024, 256, 0, stream>>>(Sfull, cnt, sidx);
  // ---- gathered sparse attention (bf16 K/V, K LDS-staged once/block) ----
  attn_kernel<<<BT * 4, 256, 0, stream>>>(qbuf, kvb, cnt, sidx, yg);
  // ---- gating v2 (32 rows/block, writes bf16 ygb directly) ----
  gate_kernel<<<(BT / 32) * 16, 256, 0, stream>>>(yg, ygb, gate_w, gate_b);
  // ---- o-proj (bf16 MFMA; wT overwrite is after attn in stream order) ----
  transpose_bf16_kernel<<<dim3(64, 64), 256, 0, stream>>>(w_o, wT, 2048, 2048);
  mfma_gemm_bt<<<dim3(16, 32), 256, 0, stream>>>(ygb, wT, b_o, (float*)d_out,
                                                 BT, 2048, 2048);
}